// Round 1
// baseline (394.521 us; speedup 1.0000x reference)
//
#include <hip/hip_runtime.h>
#include <hip/hip_bf16.h>
#include <stdint.h>

// Problem constants
constexpr int BATCH = 64;
constexpr int NTOK  = 197;
constexpr int CDIM  = 768;
constexpr int NH    = 12;
constexpr int HD    = 64;
constexpr int MROWS = BATCH * NTOK;        // 12608
constexpr int MPAD  = 12800;               // 50 * 256  (256-row GEMM tiles)
constexpr int NROWT = MPAD / 256;          // 50
constexpr int LEFT  = 137;                 // int(0.7 * 196)
constexpr int KPAD  = 224;                 // keys padded (7 * 32)
constexpr int BH    = BATCH * NH;          // 768
constexpr int SPAD  = 208;                 // score row stride
constexpr int NT    = CDIM / 64;           // 12 K-tiles of 64

// Output layout (flat float32, concatenated in return order)
constexpr size_t OUT_OFF_OUT   = 0;                                   // [64,197,768]
constexpr size_t OUT_OFF_INDEX = (size_t)BATCH * NTOK * CDIM;         // [64,137,768]
constexpr size_t OUT_OFF_IDX   = OUT_OFF_INDEX + (size_t)BATCH * LEFT * CDIM; // [64,137]
constexpr size_t OUT_OFF_CLS   = OUT_OFF_IDX + (size_t)BATCH * LEFT;  // [64,196]

// Workspace layout (float units; bf16 regions counted as elems/2)
constexpr size_t WS_CLSPH = 0;                                        // B*H*196
constexpr size_t WS_CLSF  = WS_CLSPH + (size_t)BH * (NTOK - 1);
constexpr size_t WS_IDXI  = WS_CLSF  + (size_t)BATCH * (NTOK - 1);
constexpr size_t WS_Q0    = WS_IDXI  + (size_t)BATCH * LEFT;          // [64,768]
constexpr size_t WS_XB    = WS_Q0  + (size_t)BATCH * CDIM;            // [MPAD,768] bf16
constexpr size_t WS_WB    = WS_XB  + (size_t)MPAD * CDIM / 2;         // [2304,768] bf16
constexpr size_t WS_PB    = WS_WB  + (size_t)3 * CDIM * CDIM / 2;     // [768,768] bf16
constexpr size_t WS_QB    = WS_PB  + (size_t)CDIM * CDIM / 2;         // [BH,197,64] bf16
constexpr size_t WS_KB    = WS_QB  + (size_t)BH * NTOK * HD / 2;      // [BH,197,64] bf16
constexpr size_t WS_VTB   = WS_KB  + (size_t)BH * NTOK * HD / 2;      // [BH,64,224] bf16
constexpr size_t WS_AOB   = WS_VTB + (size_t)BH * HD * KPAD / 2;      // [MPAD,768] bf16
constexpr size_t WS_U     = WS_AOB + (size_t)MPAD * CDIM / 2;         // [BH,768] fp32
constexpr size_t WS_S     = WS_U   + (size_t)BH * CDIM;               // [BH,208] fp32

typedef __attribute__((ext_vector_type(8))) short short8;
typedef __attribute__((ext_vector_type(4))) float floatx4;

__device__ __forceinline__ ushort f2bf(float x) {
    __hip_bfloat16 h = __float2bfloat16(x);
    return *(ushort*)&h;
}

// async global->LDS, 16B per lane; LDS dest must be wave-uniform base + lane*16
__device__ __forceinline__ void load_lds16(const ushort* g, ushort* l) {
    __builtin_amdgcn_global_load_lds(
        (const __attribute__((address_space(1))) uint32_t*)(uintptr_t)g,
        (__attribute__((address_space(3))) uint32_t*)(uint32_t)(uintptr_t)l,
        16, 0, 0);
}

// ---------------------------------------------------------------------------
// fp32 -> bf16 cast, zero padding up to npad4 float4s.
// ---------------------------------------------------------------------------
__global__ __launch_bounds__(256) void cast_kernel(const float* __restrict__ src,
                                                   ushort* __restrict__ dst,
                                                   int n4, int npad4) {
    int i = blockIdx.x * 256 + threadIdx.x;
    if (i >= npad4) return;
    ushort4 h4 = make_ushort4(0, 0, 0, 0);
    if (i < n4) {
        float4 a = ((const float4*)src)[i];
        h4 = make_ushort4(f2bf(a.x), f2bf(a.y), f2bf(a.z), f2bf(a.w));
    }
    ((ushort4*)dst)[i] = h4;
}

// zero the padded key columns of Vt (cols 197..223) — poison would NaN the PV MFMA
__global__ void vt_pad_kernel(ushort* __restrict__ Vtb) {
    int tid = blockIdx.x * 256 + threadIdx.x;
    constexpr int PADW = KPAD - NTOK;               // 27
    if (tid >= BH * HD * PADW) return;
    int row = tid / PADW;
    int col = NTOK + (tid - row * PADW);
    Vtb[(size_t)row * KPAD + col] = 0;
}

// ---------------------------------------------------------------------------
// Exact fp32 q row-0 projection: q0[b, c] = x[b,0,:] . qkv_w[c,:] + qkv_b[c]
// ---------------------------------------------------------------------------
__global__ __launch_bounds__(256) void q0_kernel(const float* __restrict__ x,
                                                 const float* __restrict__ qkv_w,
                                                 const float* __restrict__ qkv_b,
                                                 float* __restrict__ q0) {
    int tid = blockIdx.x * 256 + threadIdx.x;
    if (tid >= BATCH * CDIM) return;
    int b = tid / CDIM, c = tid - b * CDIM;
    const float* xr = x + (size_t)b * NTOK * CDIM;
    const float* wr = qkv_w + (size_t)c * CDIM;
    float s = 0.f;
    for (int k = 0; k < CDIM; k += 4) {
        float4 xv = *(const float4*)(xr + k);
        float4 wv = *(const float4*)(wr + k);
        s += xv.x * wv.x + xv.y * wv.y + xv.z * wv.z + xv.w * wv.w;
    }
    q0[tid] = s + qkv_b[c];
}

// ---------------------------------------------------------------------------
// u[bh, c] = sum_d q0[b, h*64+d] * Wk[h*64+d, c]   (Wk = qkv_w rows 768..1535)
// ---------------------------------------------------------------------------
__global__ __launch_bounds__(256) void u_kernel(const float* __restrict__ q0,
                                                const float* __restrict__ qkv_w,
                                                float* __restrict__ U) {
    const int bh = blockIdx.x;
    const int b  = bh / NH;
    const int h  = bh - b * NH;
    const int t  = threadIdx.x;

    __shared__ float q0s[HD];
    if (t < HD) q0s[t] = q0[(size_t)b * CDIM + h * HD + t];
    __syncthreads();

    const float* wk = qkv_w + (size_t)(CDIM + h * HD) * CDIM;
    float a0 = 0.f, a1 = 0.f, a2 = 0.f;
    for (int d = 0; d < HD; d++) {
        const float qd = q0s[d];
        const float* row = wk + (size_t)d * CDIM;
        a0 = fmaf(qd, row[t],       a0);
        a1 = fmaf(qd, row[t + 256], a1);
        a2 = fmaf(qd, row[t + 512], a2);
    }
    float* ub = U + (size_t)bh * CDIM;
    ub[t] = a0; ub[t + 256] = a1; ub[t + 512] = a2;
}

// ---------------------------------------------------------------------------
// S[bh, j] = u[bh,:] . x[b,j,:]   — 4 waves per block, one (j,b) per wave.
// ---------------------------------------------------------------------------
__global__ __launch_bounds__(256) void score_kernel(const float* __restrict__ x,
                                                    const float* __restrict__ U,
                                                    float* __restrict__ S) {
    const int wv   = threadIdx.x >> 6;
    const int lane = threadIdx.x & 63;
    const int j    = blockIdx.x * 4 + wv;
    const int b    = blockIdx.y;
    if (j >= NTOK) return;

    const float* xr = x + ((size_t)b * NTOK + j) * CDIM;
    float4 xv[3];
#pragma unroll
    for (int i = 0; i < 3; i++) xv[i] = *(const float4*)(xr + lane * 4 + i * 256);

    for (int h = 0; h < NH; h++) {
        const float* ur = U + (size_t)(b * NH + h) * CDIM;
        float s = 0.f;
#pragma unroll
        for (int i = 0; i < 3; i++) {
            float4 uv = *(const float4*)(ur + lane * 4 + i * 256);
            s += xv[i].x * uv.x + xv[i].y * uv.y + xv[i].z * uv.z + xv[i].w * uv.w;
        }
#pragma unroll
        for (int off = 32; off >= 1; off >>= 1) s += __shfl_xor(s, off);
        if (lane == 0) S[(size_t)(b * NH + h) * SPAD + j] = s;
    }
}

// ---------------------------------------------------------------------------
// Softmax of cls row per bh: s_j = (S[j] + q0_h.bk_h) * scale; probs for j>=1.
// ---------------------------------------------------------------------------
__global__ __launch_bounds__(64) void cls_softmax_kernel(const float* __restrict__ S,
                                                         const float* __restrict__ q0,
                                                         const float* __restrict__ qkv_b,
                                                         float* __restrict__ CLSPH) {
    const int bh   = blockIdx.x;
    const int b    = bh / NH;
    const int h    = bh - b * NH;
    const int lane = threadIdx.x;

    float qb = q0[(size_t)b * CDIM + h * HD + lane] * qkv_b[CDIM + h * HD + lane];
#pragma unroll
    for (int off = 32; off >= 1; off >>= 1) qb += __shfl_xor(qb, off);

    const float* Sr = S + (size_t)bh * SPAD;
    float sv[4];
    float mloc = -INFINITY;
#pragma unroll
    for (int i = 0; i < 4; i++) {
        const int j = lane + i * 64;
        sv[i] = (j < NTOK) ? (Sr[j] + qb) * 0.125f : -INFINITY;
        mloc = fmaxf(mloc, sv[i]);
    }
#pragma unroll
    for (int off = 32; off >= 1; off >>= 1) mloc = fmaxf(mloc, __shfl_xor(mloc, off));

    float pv[4], ls = 0.f;
#pragma unroll
    for (int i = 0; i < 4; i++) { pv[i] = expf(sv[i] - mloc); ls += pv[i]; }  // exp(-inf)=0
#pragma unroll
    for (int off = 32; off >= 1; off >>= 1) ls += __shfl_xor(ls, off);

    const float inv = 1.f / ls;
#pragma unroll
    for (int i = 0; i < 4; i++) {
        const int j = lane + i * 64;
        if (j >= 1 && j < NTOK)
            CLSPH[(size_t)bh * (NTOK - 1) + (j - 1)] = pv[i] * inv;
    }
}

// ---------------------------------------------------------------------------
// 256x256 / BK=64 / 8-wave / 4-phase-per-K-tile bf16 MFMA GEMM (m201 template).
// O = A @ W^T + bias.  512 threads (2M x 4N waves, each owns 128x64 of C).
// - LDS 128 KiB: sA[2][256][64], sB[2][256][64] (double-buffered K-tiles).
// - T2 swizzle: physical 16B slot = logical slot ^ (row&7). gload_lds writes
//   linearly, so the *global source* is inverse-swizzled (rule #21) and the
//   ds_read applies the same XOR -> uniform 8 dwords/bank (conflict-free b128).
// - Counted vmcnt: per K-tile period stage B-halves(t+1) in ph1/ph2 (other
//   buffer, safe after period barrier) and A-halves(t+2) in ph4 (same buffer
//   as tile t — safe only after post-ph3 barrier, when all reads of it are
//   done). One s_waitcnt vmcnt(4) per period — never 0 in the main loop.
// - T5 setprio(1) around each 16-MFMA cluster.
// MODE 0: fp32 row-major O0f[Mvalid, N].
// MODE 1: qkv scatter (bf16): q -> O0q[bh][tok][64], k -> O1k[bh][tok][64],
//         v -> O2vt[bh][d][KPAD]  (transposed!)
// ---------------------------------------------------------------------------
template <int MODE, int NCOLT>
__global__ __launch_bounds__(512, 2) void mfma_gemm256(
    const ushort* __restrict__ A, const ushort* __restrict__ W,
    const float* __restrict__ bias,
    float* __restrict__ O0f, ushort* __restrict__ O0q,
    ushort* __restrict__ O1k, ushort* __restrict__ O2vt,
    int Mvalid, int N) {
    constexpr int K = CDIM;                 // 768
    __shared__ ushort sA[2 * 256 * 64];     // 64 KiB
    __shared__ ushort sB[2 * 256 * 64];     // 64 KiB

    const int t    = threadIdx.x;
    const int lane = t & 63;
    const int w    = t >> 6;
    const int wm   = w >> 2;                // 0..1   M-half of tile
    const int wn   = w & 3;                 // 0..3   N-quarter of tile
    const int fr   = lane & 15;
    const int fq   = lane >> 4;             // 0..3

    // bijective XCD-aware swizzle (m204): contiguous wgid chunk per XCD
    int row, col;
    {
        constexpr int nwg = NROWT * NCOLT;
        constexpr int q = nwg >> 3, r = nwg & 7;
        const int xcd = blockIdx.x & 7, lin = blockIdx.x >> 3;
        const int wg = (xcd < r ? xcd * (q + 1) : r * (q + 1) + (xcd - r) * q) + lin;
        row = wg / NCOLT; col = wg - row * NCOLT;
    }
    const int rowBase = row * 256;
    const int colBase = col * 256;

    // stage one 128-row half-tile (16 KB): linear LDS dest, inverse-swz source
    auto stage = [&](const ushort* __restrict__ G, ushort* dst, int grow0, int kt) {
#pragma unroll
        for (int i = 0; i < 2; ++i) {
            const int l  = i * 512 + t;
            const int rl = l >> 3;                       // row within half
            const int sl = (l & 7) ^ (rl & 7);           // logical 16B slot
            load_lds16(G + (size_t)(grow0 + rl) * K + kt * 64 + sl * 8,
                       dst + l * 8);
        }
    };

    floatx4 acc[8][4];
#pragma unroll
    for (int m = 0; m < 8; ++m)
#pragma unroll
        for (int n = 0; n < 4; ++n)
#pragma unroll
            for (int r2 = 0; r2 < 4; ++r2) acc[m][n][r2] = 0.f;

    // read-side swizzled slot offsets (ushort units)
    const int f7   = lane & 7;
    const int s0   = (fq ^ f7) * 8;          // ks=0: logical slot fq
    const int s1   = ((4 + fq) ^ f7) * 8;    // ks=1: logical slot 4+fq
    const int aOff = (wm * 128 + fr) * 64;
    const int bOff = (wn * 64 + fr) * 64;

    // prologue: tile0 (A+B) -> buf0, tile1 A-halves -> buf1; drain tile0 only
    stage(A, sA,                rowBase,       0);
    stage(A, sA + 8192,         rowBase + 128, 0);
    stage(W, sB,                colBase,       0);
    stage(W, sB + 8192,         colBase + 128, 0);
    stage(A, sA + 16384,        rowBase,       1);
    stage(A, sA + 16384 + 8192, rowBase + 128, 1);
    asm volatile("s_waitcnt vmcnt(4)" ::: "memory");
    __builtin_amdgcn_s_barrier();
    asm volatile("" ::: "memory");

#pragma unroll 2
    for (int kt = 0; kt < NT; ++kt) {
        const int cb = (kt & 1) << 14;      // current buffer (ushort offset)
        const int nb = cb ^ 16384;          // other buffer
        const ushort* pa = sA + cb + aOff;
        const ushort* pb = sB + cb + bOff;
        short8 af[8][2], bf[4][2];

        // ---- phase 1: read A[0-3], B[0-1]; stage B-h0(kt+1) -> other buf
#pragma unroll
        for (int m = 0; m < 4; ++m) {
            af[m][0] = *(const short8*)(pa + m * 1024 + s0);
            af[m][1] = *(const short8*)(pa + m * 1024 + s1);
        }
#pragma unroll
        for (int n = 0; n < 2; ++n) {
            bf[n][0] = *(const short8*)(pb + n * 1024 + s0);
            bf[n][1] = *(const short8*)(pb + n * 1024 + s1);
        }
        if (kt + 1 < NT) stage(W, sB + nb, colBase, kt + 1);
        __builtin_amdgcn_s_barrier();
        asm volatile("s_waitcnt lgkmcnt(0)" ::: "memory");
        __builtin_amdgcn_sched_barrier(0);
        __builtin_amdgcn_s_setprio(1);
#pragma unroll
        for (int ks = 0; ks < 2; ++ks)
#pragma unroll
            for (int m = 0; m < 4; ++m)
#pragma unroll
                for (int n = 0; n < 2; ++n)
                    acc[m][n] = __builtin_amdgcn_mfma_f32_16x16x32_bf16(
                        af[m][ks], bf[n][ks], acc[m][n], 0, 0, 0);
        __builtin_amdgcn_s_setprio(0);
        __builtin_amdgcn_s_barrier();
        asm volatile("" ::: "memory");

        // ---- phase 2: read B[2-3]; stage B-h1(kt+1) -> other buf
#pragma unroll
        for (int n = 2; n < 4; ++n) {
            bf[n][0] = *(const short8*)(pb + n * 1024 + s0);
            bf[n][1] = *(const short8*)(pb + n * 1024 + s1);
        }
        if (kt + 1 < NT) stage(W, sB + nb + 8192, colBase + 128, kt + 1);
        __builtin_amdgcn_s_barrier();
        asm volatile("s_waitcnt lgkmcnt(0)" ::: "memory");
        __builtin_amdgcn_sched_barrier(0);
        __builtin_amdgcn_s_setprio(1);
#pragma unroll
        for (int ks = 0; ks < 2; ++ks)
#pragma unroll
            for (int m = 0; m < 4; ++m)
#pragma unroll
                for (int n = 2; n < 4; ++n)
                    acc[m][n] = __builtin_amdgcn_mfma_f32_16x16x32_bf16(
                        af[m][ks], bf[n][ks], acc[m][n], 0, 0, 0);
        __builtin_amdgcn_s_setprio(0);
        __builtin_amdgcn_s_barrier();
        asm volatile("" ::: "memory");

        // ---- phase 3: read A[4-7] (last reads of current buffer)
#pragma unroll
        for (int m = 4; m < 8; ++m) {
            af[m][0] = *(const short8*)(pa + m * 1024 + s0);
            af[m][1] = *(const short8*)(pa + m * 1024 + s1);
        }
        __builtin_amdgcn_s_barrier();
        asm volatile("s_waitcnt lgkmcnt(0)" ::: "memory");
        __builtin_amdgcn_sched_barrier(0);
        __builtin_amdgcn_s_setprio(1);
#pragma unroll
        for (int ks = 0; ks < 2; ++ks)
#pragma unroll
            for (int m = 4; m < 8; ++m)
#pragma unroll
                for (int n = 0; n < 2; ++n)
                    acc[m][n] = __builtin_amdgcn_mfma_f32_16x16x32_bf16(
                        af[m][ks], bf[n][ks], acc[m][n], 0, 0, 0);
        __builtin_amdgcn_s_setprio(0);
        __builtin_amdgcn_s_barrier();
        asm volatile("" ::: "memory");

        // ---- phase 4: stage A(kt+2) into CURRENT buffer (reads done);
        //      counted drain of tile kt+1, then compute last quadrant.
        if (kt + 2 < NT) {
            stage(A, sA + cb,        rowBase,       kt + 2);
            stage(A, sA + cb + 8192, rowBase + 128, kt + 2);
            asm volatile("s_waitcnt vmcnt(4)" ::: "memory");
        } else if (kt + 1 < NT) {
            asm volatile("s_waitcnt vmcnt(0)" ::: "memory");
        }
        __builtin_amdgcn_s_barrier();
        asm volatile("" ::: "memory");
        __builtin_amdgcn_s_setprio(1);
#pragma unroll
        for (int ks = 0; ks < 2; ++ks)
#pragma unroll
            for (int m = 4; m < 8; ++m)
#pragma unroll
                for (int n = 2; n < 4; ++n)
                    acc[m][n] = __builtin_amdgcn_mfma_f32_16x16x32_bf16(
                        af[m][ks], bf[n][ks], acc[m][n], 0, 0, 0);
        __builtin_amdgcn_s_setprio(0);
        __builtin_amdgcn_s_barrier();
        asm volatile("" ::: "memory");
    }

    // epilogue: C/D layout col(n)=lane&15, row(m)=(lane>>4)*4+reg
#pragma unroll
    for (int n = 0; n < 4; ++n) {
        const int nn = colBase + wn * 64 + n * 16 + fr;
        const float bq = bias[nn];
        if (MODE == 0) {
#pragma unroll
            for (int m = 0; m < 8; ++m) {
                const int mb = rowBase + wm * 128 + m * 16 + fq * 4;
#pragma unroll
                for (int r2 = 0; r2 < 4; ++r2) {
                    const int mm = mb + r2;
                    if (mm < Mvalid) O0f[(size_t)mm * N + nn] = acc[m][n][r2] + bq;
                }
            }
        } else {
            const int which = nn / CDIM;
            const int nc    = nn - which * CDIM;
            const int h     = nc >> 6;
            const int d     = nc & 63;
#pragma unroll
            for (int m = 0; m < 8; ++m) {
                const int mb = rowBase + wm * 128 + m * 16 + fq * 4;
#pragma unroll
                for (int r2 = 0; r2 < 4; ++r2) {
                    const int mm = mb + r2;
                    if (mm < Mvalid) {
                        const int b   = mm / NTOK;
                        const int tok = mm - b * NTOK;
                        const int bh  = b * NH + h;
                        const ushort val = f2bf(acc[m][n][r2] + bq);
                        if (which == 0)      O0q[((size_t)bh * NTOK + tok) * HD + d] = val;
                        else if (which == 1) O1k[((size_t)bh * NTOK + tok) * HD + d] = val;
                        else                 O2vt[((size_t)bh * HD + d) * KPAD + tok] = val;
                    }
                }
            }
        }
    }
}

// ---------------------------------------------------------------------------
// MFMA flash attention: one wave (64 threads) per (q-tile, b*h).
// S^T = K.Q^T so queries sit in C-columns; online softmax per-lane + two
// shfl_xor quad-reduces. P via 1KB LDS roundtrip; PV uses transposed-V frags.
// ---------------------------------------------------------------------------
__global__ __launch_bounds__(64) void attn_mfma_kernel(const ushort* __restrict__ Qb,
                                                       const ushort* __restrict__ Kb,
                                                       const ushort* __restrict__ Vtb,
                                                       ushort* __restrict__ AOb) {
    const int qt = blockIdx.x;          // 0..12
    const int bh = blockIdx.y;          // 0..767
    const int b  = bh / NH;
    const int h  = bh - b * NH;
    const int lane = threadIdx.x;
    const int qc   = lane & 15;
    const int quad = lane >> 4;

    __shared__ ushort Pl[16][32];
    __shared__ float  alf[16], lf[16];

    const ushort* Qh = Qb  + (size_t)bh * NTOK * HD;
    const ushort* Kh = Kb  + (size_t)bh * NTOK * HD;
    const ushort* Vh = Vtb + (size_t)bh * HD * KPAD;

    const int qrow = min(qt * 16 + qc, NTOK - 1);
    const short8 qf0 = *(const short8*)(Qh + (size_t)qrow * HD + quad * 8);
    const short8 qf1 = *(const short8*)(Qh + (size_t)qrow * HD + 32 + quad * 8);

    floatx4 o[4];
#pragma unroll
    for (int s = 0; s < 4; s++)
#pragma unroll
        for (int r = 0; r < 4; r++) o[s][r] = 0.f;
    float m = -INFINITY, l = 0.f;

    for (int c0 = 0; c0 < NTOK; c0 += 32) {
        const int kr0 = min(c0 + qc, NTOK - 1);
        const int kr1 = min(c0 + 16 + qc, NTOK - 1);
        short8 kf00 = *(const short8*)(Kh + (size_t)kr0 * HD + quad * 8);
        short8 kf01 = *(const short8*)(Kh + (size_t)kr0 * HD + 32 + quad * 8);
        short8 kf10 = *(const short8*)(Kh + (size_t)kr1 * HD + quad * 8);
        short8 kf11 = *(const short8*)(Kh + (size_t)kr1 * HD + 32 + quad * 8);

        floatx4 s0 = {0.f, 0.f, 0.f, 0.f}, s1 = {0.f, 0.f, 0.f, 0.f};
        s0 = __builtin_amdgcn_mfma_f32_16x16x32_bf16(kf00, qf0, s0, 0, 0, 0);
        s0 = __builtin_amdgcn_mfma_f32_16x16x32_bf16(kf01, qf1, s0, 0, 0, 0);
        s1 = __builtin_amdgcn_mfma_f32_16x16x32_bf16(kf10, qf0, s1, 0, 0, 0);
        s1 = __builtin_amdgcn_mfma_f32_16x16x32_bf16(kf11, qf1, s1, 0, 0, 0);

        float sv[8];
        float mloc = -INFINITY;
#pragma unroll
        for (int r = 0; r < 4; r++) {
            const int key0 = c0 + quad * 4 + r;
            const int key1 = key0 + 16;
            sv[r]     = (key0 < NTOK) ? s0[r] * 0.125f : -1e30f;
            sv[4 + r] = (key1 < NTOK) ? s1[r] * 0.125f : -1e30f;
            mloc = fmaxf(mloc, fmaxf(sv[r], sv[4 + r]));
        }
        mloc = fmaxf(mloc, __shfl_xor(mloc, 16));
        mloc = fmaxf(mloc, __shfl_xor(mloc, 32));
        const float mnew  = fmaxf(m, mloc);
        const float alpha = __expf(m - mnew);
        float p[8], ps = 0.f;
#pragma unroll
        for (int i = 0; i < 8; i++) { p[i] = __expf(sv[i] - mnew); ps += p[i]; }
        ps += __shfl_xor(ps, 16);
        ps += __shfl_xor(ps, 32);
        l = l * alpha + ps;
        m = mnew;

#pragma unroll
        for (int r = 0; r < 4; r++) {
            Pl[qc][quad * 4 + r]      = f2bf(p[r]);
            Pl[qc][16 + quad * 4 + r] = f2bf(p[4 + r]);
        }
        if (quad == 0) alf[qc] = alpha;
        __syncthreads();

        float ar[4];
#pragma unroll
        for (int r = 0; r < 4; r++) ar[r] = alf[quad * 4 + r];
#pragma unroll
        for (int s = 0; s < 4; s++)
#pragma unroll
            for (int r = 0; r < 4; r++) o[s][r] *= ar[r];

        const short8 pf = *(const short8*)&Pl[qc][quad * 8];
#pragma unroll
        for (int s = 0; s < 4; s++) {
            const short8 vf = *(const short8*)(Vh + (size_t)(s * 16 + qc) * KPAD + c0 + quad * 8);
            o[s] = __builtin_amdgcn_mfma_f32_16x16x32_bf16(pf, vf, o[s], 0, 0, 0);
        }
        __syncthreads();
    }

    if (quad == 0) lf[qc] = l;
    __syncthreads();

#pragma unroll
    for (int r = 0; r < 4; r++) {
        const int tok = qt * 16 + quad * 4 + r;
        if (tok >= NTOK) continue;
        const float inv = 1.f / lf[quad * 4 + r];
        ushort* dst = AOb + ((size_t)(b * NTOK + tok)) * CDIM + h * HD;
#pragma unroll
        for (int s = 0; s < 4; s++) dst[s * 16 + qc] = f2bf(o[s][r] * inv);
    }
}

// ---------------------------------------------------------------------------
__global__ void cls_mean_kernel(const float* __restrict__ CLSPH,
                                float* __restrict__ clsF,
                                float* __restrict__ outCls) {
    int tid = blockIdx.x * 256 + threadIdx.x;
    if (tid >= BATCH * (NTOK - 1)) return;
    int b = tid / (NTOK - 1);
    int j = tid - b * (NTOK - 1);
    float s = 0.f;
#pragma unroll
    for (int h = 0; h < NH; h++) s += CLSPH[(size_t)(b * NH + h) * (NTOK - 1) + j];
    float v = s * (1.f / 12.f);
    clsF[tid]   = v;
    outCls[tid] = v;
}

__global__ void topk_kernel(const float* __restrict__ clsF,
                            int* __restrict__ idxI,
                            float* __restrict__ idxOut) {
    const int b = blockIdx.x;
    const int t = threadIdx.x;
    __shared__ float v[NTOK - 1];
    if (t < NTOK - 1) v[t] = clsF[b * (NTOK - 1) + t];
    __syncthreads();
    if (t < NTOK - 1) {
        float vi = v[t];
        int rank = 0;
        for (int j = 0; j < NTOK - 1; j++) {
            float vj = v[j];
            rank += (vj > vi) || (vj == vi && j < t);
        }
        if (rank < LEFT) {
            idxI[b * LEFT + rank]   = t;
            idxOut[b * LEFT + rank] = (float)t;
        }
    }
}

// index = broadcast idx over channel dim, float4-vectorized (CDIM%4==0)
__global__ void fill_index_kernel(const int* __restrict__ idxI,
                                  float* __restrict__ dst) {
    int tid = blockIdx.x * 256 + threadIdx.x;
    constexpr int C4 = CDIM / 4;
    if (tid >= BATCH * LEFT * C4) return;
    float v = (float)idxI[tid / C4];
    ((float4*)dst)[tid] = make_float4(v, v, v, v);
}

extern "C" void kernel_launch(void* const* d_in, const int* in_sizes, int n_in,
                              void* d_out, int out_size, void* d_ws, size_t ws_size,
                              hipStream_t stream) {
    const float* x      = (const float*)d_in[0];
    const float* qkv_w  = (const float*)d_in[1];  // [2304,768]
    const float* qkv_b  = (const float*)d_in[2];  // [2304]
    const float* proj_w = (const float*)d_in[3];  // [768,768]
    const float* proj_b = (const float*)d_in[4];  // [768]
    float* out = (float*)d_out;

    float*  ws    = (float*)d_ws;
    float*  clsph = ws + WS_CLSPH;
    float*  clsf  = ws + WS_CLSF;
    int*    idxi  = (int*)(ws + WS_IDXI);
    float*  q0    = ws + WS_Q0;
    ushort* xb    = (ushort*)(ws + WS_XB);
    ushort* wb    = (ushort*)(ws + WS_WB);
    ushort* pb    = (ushort*)(ws + WS_PB);
    ushort* qb    = (ushort*)(ws + WS_QB);
    ushort* kb    = (ushort*)(ws + WS_KB);
    ushort* vtb   = (ushort*)(ws + WS_VTB);
    ushort* aob   = (ushort*)(ws + WS_AOB);
    float*  U     = ws + WS_U;
    float*  S     = ws + WS_S;

    // 1) fp32 -> bf16 casts (+row padding to MPAD), Vt pad-column zeroing
    {
        int n4 = MROWS * CDIM / 4, np4 = MPAD * CDIM / 4;
        cast_kernel<<<(np4 + 255) / 256, 256, 0, stream>>>(x, xb, n4, np4);
        int w4 = 3 * CDIM * CDIM / 4;
        cast_kernel<<<(w4 + 255) / 256, 256, 0, stream>>>(qkv_w, wb, w4, w4);
        int p4 = CDIM * CDIM / 4;
        cast_kernel<<<(p4 + 255) / 256, 256, 0, stream>>>(proj_w, pb, p4, p4);
        int vp = BH * HD * (KPAD - NTOK);
        vt_pad_kernel<<<(vp + 255) / 256, 256, 0, stream>>>(vtb);
    }

    // 2) Exact fp32 cls-score side path (top-k precision domain)
    q0_kernel<<<(BATCH * CDIM + 255) / 256, 256, 0, stream>>>(x, qkv_w, qkv_b, q0);
    u_kernel<<<BH, 256, 0, stream>>>(q0, qkv_w, U);
    score_kernel<<<dim3((NTOK + 3) / 4, BATCH), 256, 0, stream>>>(x, U, S);
    cls_softmax_kernel<<<BH, 64, 0, stream>>>(S, q0, qkv_b, clsph);

    // 3) QKV projection (256² 8-phase bf16 MFMA) + scatter q/k bf16, v transposed
    mfma_gemm256<1, 9><<<NROWT * 9, 512, 0, stream>>>(
        xb, wb, qkv_b, nullptr, qb, kb, vtb, MROWS, 3 * CDIM);

    // 4) MFMA flash attention -> bf16 pre-proj out
    attn_mfma_kernel<<<dim3(13, BH), 64, 0, stream>>>(qb, kb, vtb, aob);

    // 5) Output projection (256² 8-phase bf16 MFMA) -> fp32 out
    mfma_gemm256<0, 3><<<NROWT * 3, 512, 0, stream>>>(
        aob, pb, proj_b, out + OUT_OFF_OUT, nullptr, nullptr, nullptr,
        MROWS, CDIM);

    // 6) Head-average cls attention (exact path)
    cls_mean_kernel<<<(BATCH * (NTOK - 1) + 255) / 256, 256, 0, stream>>>(
        clsph, clsf, out + OUT_OFF_CLS);

    // 7) Exact top-137 (stable descending)
    topk_kernel<<<BATCH, 256, 0, stream>>>(clsf, idxi, out + OUT_OFF_IDX);

    // 8) Broadcast indices over channels (float4)
    fill_index_kernel<<<((size_t)BATCH * LEFT * (CDIM / 4) + 255) / 256, 256, 0, stream>>>(
        idxi, out + OUT_OFF_INDEX);
}

// Round 3
// 386.577 us; speedup vs baseline: 1.0205x; 1.0205x over previous
//
#include <hip/hip_runtime.h>
#include <hip/hip_bf16.h>
#include <stdint.h>

// Problem constants
constexpr int BATCH = 64;
constexpr int NTOK  = 197;
constexpr int CDIM  = 768;
constexpr int NH    = 12;
constexpr int HD    = 64;
constexpr int MROWS = BATCH * NTOK;        // 12608
constexpr int MPAD  = 12800;               // 100 * 128 (GEMM row tiles)
constexpr int NROWT = MPAD / 128;          // 100
constexpr int LEFT  = 137;                 // int(0.7 * 196)
constexpr int KPAD  = 224;                 // keys padded (7 * 32)
constexpr int BH    = BATCH * NH;          // 768
constexpr int SPAD  = 208;                 // score row stride
constexpr int NT    = CDIM / 64;           // 12 K-tiles of 64

// Output layout (flat float32, concatenated in return order)
constexpr size_t OUT_OFF_OUT   = 0;                                   // [64,197,768]
constexpr size_t OUT_OFF_INDEX = (size_t)BATCH * NTOK * CDIM;         // [64,137,768]
constexpr size_t OUT_OFF_IDX   = OUT_OFF_INDEX + (size_t)BATCH * LEFT * CDIM; // [64,137]
constexpr size_t OUT_OFF_CLS   = OUT_OFF_IDX + (size_t)BATCH * LEFT;  // [64,196]

// Workspace layout (float units; bf16 regions counted as elems/2)
constexpr size_t WS_CLSPH = 0;                                        // B*H*196
constexpr size_t WS_CLSF  = WS_CLSPH + (size_t)BH * (NTOK - 1);
constexpr size_t WS_IDXI  = WS_CLSF  + (size_t)BATCH * (NTOK - 1);
constexpr size_t WS_Q0    = WS_IDXI  + (size_t)BATCH * LEFT;          // [64,768]
constexpr size_t WS_XB    = WS_Q0  + (size_t)BATCH * CDIM;            // [MPAD,768] bf16
constexpr size_t WS_WB    = WS_XB  + (size_t)MPAD * CDIM / 2;         // [2304,768] bf16
constexpr size_t WS_PB    = WS_WB  + (size_t)3 * CDIM * CDIM / 2;     // [768,768] bf16
constexpr size_t WS_QB    = WS_PB  + (size_t)CDIM * CDIM / 2;         // [BH,197,64] bf16
constexpr size_t WS_KB    = WS_QB  + (size_t)BH * NTOK * HD / 2;      // [BH,197,64] bf16
constexpr size_t WS_VTB   = WS_KB  + (size_t)BH * NTOK * HD / 2;      // [BH,64,224] bf16
constexpr size_t WS_AOB   = WS_VTB + (size_t)BH * HD * KPAD / 2;      // [MPAD,768] bf16
constexpr size_t WS_U     = WS_AOB + (size_t)MPAD * CDIM / 2;         // [BH,768] fp32
constexpr size_t WS_S     = WS_U   + (size_t)BH * CDIM;               // [BH,208] fp32

typedef __attribute__((ext_vector_type(8))) short short8;
typedef __attribute__((ext_vector_type(4))) float floatx4;

__device__ __forceinline__ ushort f2bf(float x) {
    __hip_bfloat16 h = __float2bfloat16(x);
    return *(ushort*)&h;
}

// async global->LDS, 16B per lane; LDS dest must be wave-uniform base + lane*16
__device__ __forceinline__ void load_lds16(const ushort* g, ushort* l) {
    __builtin_amdgcn_global_load_lds(
        (const __attribute__((address_space(1))) uint32_t*)(uintptr_t)g,
        (__attribute__((address_space(3))) uint32_t*)(uint32_t)(uintptr_t)l,
        16, 0, 0);
}

// ---------------------------------------------------------------------------
// fp32 -> bf16 cast, zero padding up to npad4 float4s.
// ---------------------------------------------------------------------------
__global__ __launch_bounds__(256) void cast_kernel(const float* __restrict__ src,
                                                   ushort* __restrict__ dst,
                                                   int n4, int npad4) {
    int i = blockIdx.x * 256 + threadIdx.x;
    if (i >= npad4) return;
    ushort4 h4 = make_ushort4(0, 0, 0, 0);
    if (i < n4) {
        float4 a = ((const float4*)src)[i];
        h4 = make_ushort4(f2bf(a.x), f2bf(a.y), f2bf(a.z), f2bf(a.w));
    }
    ((ushort4*)dst)[i] = h4;
}

// ---------------------------------------------------------------------------
// Exact fp32 q row-0 projection: q0[b, c] = x[b,0,:] . qkv_w[c,:] + qkv_b[c]
// ---------------------------------------------------------------------------
__global__ __launch_bounds__(256) void q0_kernel(const float* __restrict__ x,
                                                 const float* __restrict__ qkv_w,
                                                 const float* __restrict__ qkv_b,
                                                 float* __restrict__ q0) {
    int tid = blockIdx.x * 256 + threadIdx.x;
    if (tid >= BATCH * CDIM) return;
    int b = tid / CDIM, c = tid - b * CDIM;
    const float* xr = x + (size_t)b * NTOK * CDIM;
    const float* wr = qkv_w + (size_t)c * CDIM;
    float s = 0.f;
    for (int k = 0; k < CDIM; k += 4) {
        float4 xv = *(const float4*)(xr + k);
        float4 wv = *(const float4*)(wr + k);
        s += xv.x * wv.x + xv.y * wv.y + xv.z * wv.z + xv.w * wv.w;
    }
    q0[tid] = s + qkv_b[c];
}

// ---------------------------------------------------------------------------
// u[bh, c] = sum_d q0[b, h*64+d] * Wk[h*64+d, c]   (Wk = qkv_w rows 768..1535)
// ---------------------------------------------------------------------------
__global__ __launch_bounds__(256) void u_kernel(const float* __restrict__ q0,
                                                const float* __restrict__ qkv_w,
                                                float* __restrict__ U) {
    const int bh = blockIdx.x;
    const int b  = bh / NH;
    const int h  = bh - b * NH;
    const int t  = threadIdx.x;

    __shared__ float q0s[HD];
    if (t < HD) q0s[t] = q0[(size_t)b * CDIM + h * HD + t];
    __syncthreads();

    const float* wk = qkv_w + (size_t)(CDIM + h * HD) * CDIM;
    float a0 = 0.f, a1 = 0.f, a2 = 0.f;
    for (int d = 0; d < HD; d++) {
        const float qd = q0s[d];
        const float* row = wk + (size_t)d * CDIM;
        a0 = fmaf(qd, row[t],       a0);
        a1 = fmaf(qd, row[t + 256], a1);
        a2 = fmaf(qd, row[t + 512], a2);
    }
    float* ub = U + (size_t)bh * CDIM;
    ub[t] = a0; ub[t + 256] = a1; ub[t + 512] = a2;
}

// ---------------------------------------------------------------------------
// S[bh, j] = u[bh,:] . x[b,j,:]   — 4 waves per block, one (j,b) per wave.
// ---------------------------------------------------------------------------
__global__ __launch_bounds__(256) void score_kernel(const float* __restrict__ x,
                                                    const float* __restrict__ U,
                                                    float* __restrict__ S) {
    const int wv   = threadIdx.x >> 6;
    const int lane = threadIdx.x & 63;
    const int j    = blockIdx.x * 4 + wv;
    const int b    = blockIdx.y;
    if (j >= NTOK) return;

    const float* xr = x + ((size_t)b * NTOK + j) * CDIM;
    float4 xv[3];
#pragma unroll
    for (int i = 0; i < 3; i++) xv[i] = *(const float4*)(xr + lane * 4 + i * 256);

    for (int h = 0; h < NH; h++) {
        const float* ur = U + (size_t)(b * NH + h) * CDIM;
        float s = 0.f;
#pragma unroll
        for (int i = 0; i < 3; i++) {
            float4 uv = *(const float4*)(ur + lane * 4 + i * 256);
            s += xv[i].x * uv.x + xv[i].y * uv.y + xv[i].z * uv.z + xv[i].w * uv.w;
        }
#pragma unroll
        for (int off = 32; off >= 1; off >>= 1) s += __shfl_xor(s, off);
        if (lane == 0) S[(size_t)(b * NH + h) * SPAD + j] = s;
    }
}

// ---------------------------------------------------------------------------
// Softmax of cls row per bh: s_j = (S[j] + q0_h.bk_h) * scale; probs for j>=1.
// ---------------------------------------------------------------------------
__global__ __launch_bounds__(64) void cls_softmax_kernel(const float* __restrict__ S,
                                                         const float* __restrict__ q0,
                                                         const float* __restrict__ qkv_b,
                                                         float* __restrict__ CLSPH) {
    const int bh   = blockIdx.x;
    const int b    = bh / NH;
    const int h    = bh - b * NH;
    const int lane = threadIdx.x;

    float qb = q0[(size_t)b * CDIM + h * HD + lane] * qkv_b[CDIM + h * HD + lane];
#pragma unroll
    for (int off = 32; off >= 1; off >>= 1) qb += __shfl_xor(qb, off);

    const float* Sr = S + (size_t)bh * SPAD;
    float sv[4];
    float mloc = -INFINITY;
#pragma unroll
    for (int i = 0; i < 4; i++) {
        const int j = lane + i * 64;
        sv[i] = (j < NTOK) ? (Sr[j] + qb) * 0.125f : -INFINITY;
        mloc = fmaxf(mloc, sv[i]);
    }
#pragma unroll
    for (int off = 32; off >= 1; off >>= 1) mloc = fmaxf(mloc, __shfl_xor(mloc, off));

    float pv[4], ls = 0.f;
#pragma unroll
    for (int i = 0; i < 4; i++) { pv[i] = expf(sv[i] - mloc); ls += pv[i]; }  // exp(-inf)=0
#pragma unroll
    for (int off = 32; off >= 1; off >>= 1) ls += __shfl_xor(ls, off);

    const float inv = 1.f / ls;
#pragma unroll
    for (int i = 0; i < 4; i++) {
        const int j = lane + i * 64;
        if (j >= 1 && j < NTOK)
            CLSPH[(size_t)bh * (NTOK - 1) + (j - 1)] = pv[i] * inv;
    }
}

// ---------------------------------------------------------------------------
// 128x128 / BK=64 / 4-wave bf16 MFMA GEMM, m97-style single-sync double-buffer
// loop (compiler-managed waitcnt), 64 KiB LDS -> 2 blocks/CU resident so
// cross-block wave overlap (m114) hides the per-K-step barrier drain.
// - T2 XOR swizzle: phys 16B slot = logical slot ^ (row&7); gload_lds writes
//   linearly so the *global source* is inverse-swizzled and the ds_read
//   applies the same XOR (rule #21).
// - bijective XCD-aware block swizzle for A-panel L2 locality.
// MODE 0: fp32 row-major O0f[Mvalid, N].
// MODE 1: qkv split (bf16): q -> O0q[bh][tok][64], k -> O1k[bh][tok][64],
//         v -> DENSE O2vd[m][768] (32B-segment stores; transposed later).
// ---------------------------------------------------------------------------
template <int MODE, int NCOLT>
__global__ __launch_bounds__(256, 2) void mfma_gemm128(
    const ushort* __restrict__ A, const ushort* __restrict__ W,
    const float* __restrict__ bias,
    float* __restrict__ O0f, ushort* __restrict__ O0q,
    ushort* __restrict__ O1k, ushort* __restrict__ O2vd,
    int Mvalid, int N) {
    constexpr int K = CDIM;                 // 768
    __shared__ ushort sA[2 * 128 * 64];     // 32 KiB
    __shared__ ushort sB[2 * 128 * 64];     // 32 KiB

    const int t    = threadIdx.x;
    const int lane = t & 63;
    const int w    = t >> 6;
    const int wm   = (w >> 1) * 64;         // M-half of tile
    const int wn   = (w & 1) * 64;          // N-half of tile
    const int fr   = lane & 15;
    const int fq   = lane >> 4;             // 0..3
    const int f7   = lane & 7;

    // bijective XCD-aware swizzle (m204): contiguous wgid chunk per XCD
    int row, col;
    {
        constexpr int nwg = NROWT * NCOLT;
        constexpr int q = nwg >> 3, r = nwg & 7;
        const int xcd = blockIdx.x & 7, lin = blockIdx.x >> 3;
        const int wg = (xcd < r ? xcd * (q + 1) : r * (q + 1) + (xcd - r) * q) + lin;
        row = wg / NCOLT; col = wg - row * NCOLT;
    }
    const int rowBase = row * 128;
    const int colBase = col * 128;

    // stage one 128x64 tile (16 KB): linear LDS dest, inverse-swizzled source
    auto stage = [&](const ushort* __restrict__ G, ushort* dst, int grow0, int kt) {
#pragma unroll
        for (int i = 0; i < 4; ++i) {
            const int l  = i * 256 + t;
            const int rl = l >> 3;                       // row (8 thr/row)
            const int sl = (l & 7) ^ (rl & 7);           // swizzled 16B slot
            load_lds16(G + (size_t)(grow0 + rl) * K + kt * 64 + sl * 8,
                       dst + l * 8);
        }
    };

    floatx4 acc[4][4];
#pragma unroll
    for (int i = 0; i < 4; ++i)
#pragma unroll
        for (int j = 0; j < 4; ++j)
#pragma unroll
            for (int r2 = 0; r2 < 4; ++r2) acc[i][j][r2] = 0.f;

    // read-side swizzled slot byte offsets (ushort units), per ks half
    const int s0 = (fq ^ f7) * 8;            // ks=0: logical slot fq
    const int s1 = ((4 + fq) ^ f7) * 8;      // ks=1: logical slot 4+fq

    // prologue: tile 0 -> buffer 0
    stage(A, sA, rowBase, 0);
    stage(W, sB, colBase, 0);

    for (int kt = 0; kt < NT; ++kt) {
        __syncthreads();                     // drains vm+lgkm: buf[cur] ready,
                                             // buf[cur^1] reads complete
        const int cb = (kt & 1) << 13;       // current buffer (ushort offset)
        if (kt + 1 < NT) {                   // prefetch next tile
            stage(A, sA + (cb ^ 8192), rowBase, kt + 1);
            stage(W, sB + (cb ^ 8192), colBase, kt + 1);
        }

        const ushort* pa = sA + cb + (wm + fr) * 64;
        const ushort* pb = sB + cb + (wn + fr) * 64;
        short8 af[4][2], bf[4][2];
#pragma unroll
        for (int i = 0; i < 4; ++i) {
            af[i][0] = *(const short8*)(pa + i * 1024 + s0);
            af[i][1] = *(const short8*)(pa + i * 1024 + s1);
            bf[i][0] = *(const short8*)(pb + i * 1024 + s0);
            bf[i][1] = *(const short8*)(pb + i * 1024 + s1);
        }
#pragma unroll
        for (int ks = 0; ks < 2; ++ks)
#pragma unroll
            for (int i = 0; i < 4; ++i)
#pragma unroll
                for (int j = 0; j < 4; ++j)
                    acc[i][j] = __builtin_amdgcn_mfma_f32_16x16x32_bf16(
                        af[i][ks], bf[j][ks], acc[i][j], 0, 0, 0);
    }

    // epilogue: C/D layout col(n)=lane&15, row(m)=(lane>>4)*4+reg
#pragma unroll
    for (int j = 0; j < 4; ++j) {
        const int nn = colBase + wn + j * 16 + fr;
        const float bq = bias[nn];
        if (MODE == 0) {
#pragma unroll
            for (int i = 0; i < 4; ++i) {
                const int mb = rowBase + wm + i * 16 + fq * 4;
#pragma unroll
                for (int r2 = 0; r2 < 4; ++r2) {
                    const int mm = mb + r2;
                    if (mm < Mvalid) O0f[(size_t)mm * N + nn] = acc[i][j][r2] + bq;
                }
            }
        } else {
            const int which = nn / CDIM;     // wave-uniform per col-tile
            const int nc    = nn - which * CDIM;
            const int h     = nc >> 6;
            const int d     = nc & 63;
#pragma unroll
            for (int i = 0; i < 4; ++i) {
                const int mb = rowBase + wm + i * 16 + fq * 4;
#pragma unroll
                for (int r2 = 0; r2 < 4; ++r2) {
                    const int mm = mb + r2;
                    if (mm < Mvalid) {
                        const int b   = mm / NTOK;
                        const int tok = mm - b * NTOK;
                        const int bh  = b * NH + h;
                        const ushort val = f2bf(acc[i][j][r2] + bq);
                        if (which == 0)      O0q[((size_t)bh * NTOK + tok) * HD + d] = val;
                        else if (which == 1) O1k[((size_t)bh * NTOK + tok) * HD + d] = val;
                        else                 O2vd[(size_t)mm * CDIM + nc] = val;  // dense
                    }
                }
            }
        }
    }
}

// ---------------------------------------------------------------------------
// Vd[b*197+tok][768] (dense v, bf16) -> Vtb[bh][d][KPAD] via LDS transpose.
// Coalesced 128B row reads, 448B row writes; zero-fills pad cols 197..223
// (replaces vt_pad_kernel).
// ---------------------------------------------------------------------------
__global__ __launch_bounds__(256) void v_transpose_kernel(const ushort* __restrict__ Vd,
                                                          ushort* __restrict__ Vtb) {
    const int bh = blockIdx.x;             // 0..767
    const int b  = bh / NH;
    const int h  = bh - b * NH;
    const int t  = threadIdx.x;

    __shared__ ushort tile[HD][KPAD + 9];  // odd pad stride vs bank conflicts

    const int d  = t & 63;
    const int tt = t >> 6;                 // 0..3
    const ushort* src = Vd + (size_t)b * NTOK * CDIM + h * HD + d;
    for (int tok0 = 0; tok0 < KPAD; tok0 += 4) {
        const int tok = tok0 + tt;
        ushort v = 0;
        if (tok < NTOK) v = src[(size_t)tok * CDIM];
        tile[d][tok] = v;
    }
    __syncthreads();

    uint* dst = (uint*)(Vtb + (size_t)bh * HD * KPAD);
    constexpr int C2 = KPAD / 2;           // 112 u32 per d-row
    for (int idx = t; idx < HD * C2; idx += 256) {
        const int dd = idx / C2;
        const int c  = idx - dd * C2;
        const uint lo = tile[dd][2 * c];
        const uint hi = tile[dd][2 * c + 1];
        dst[dd * C2 + c] = lo | (hi << 16);
    }
}

// ---------------------------------------------------------------------------
// MFMA flash attention: one wave (64 threads) per (q-tile, b*h).
// S^T = K.Q^T so queries sit in C-columns; online softmax per-lane + two
// shfl_xor quad-reduces. P via 1KB LDS roundtrip; PV uses transposed-V frags.
// ---------------------------------------------------------------------------
__global__ __launch_bounds__(64) void attn_mfma_kernel(const ushort* __restrict__ Qb,
                                                       const ushort* __restrict__ Kb,
                                                       const ushort* __restrict__ Vtb,
                                                       ushort* __restrict__ AOb) {
    const int qt = blockIdx.x;          // 0..12
    const int bh = blockIdx.y;          // 0..767
    const int b  = bh / NH;
    const int h  = bh - b * NH;
    const int lane = threadIdx.x;
    const int qc   = lane & 15;
    const int quad = lane >> 4;

    __shared__ ushort Pl[16][32];
    __shared__ float  alf[16], lf[16];

    const ushort* Qh = Qb  + (size_t)bh * NTOK * HD;
    const ushort* Kh = Kb  + (size_t)bh * NTOK * HD;
    const ushort* Vh = Vtb + (size_t)bh * HD * KPAD;

    const int qrow = min(qt * 16 + qc, NTOK - 1);
    const short8 qf0 = *(const short8*)(Qh + (size_t)qrow * HD + quad * 8);
    const short8 qf1 = *(const short8*)(Qh + (size_t)qrow * HD + 32 + quad * 8);

    floatx4 o[4];
#pragma unroll
    for (int s = 0; s < 4; s++)
#pragma unroll
        for (int r = 0; r < 4; r++) o[s][r] = 0.f;
    float m = -INFINITY, l = 0.f;

    for (int c0 = 0; c0 < NTOK; c0 += 32) {
        const int kr0 = min(c0 + qc, NTOK - 1);
        const int kr1 = min(c0 + 16 + qc, NTOK - 1);
        short8 kf00 = *(const short8*)(Kh + (size_t)kr0 * HD + quad * 8);
        short8 kf01 = *(const short8*)(Kh + (size_t)kr0 * HD + 32 + quad * 8);
        short8 kf10 = *(const short8*)(Kh + (size_t)kr1 * HD + quad * 8);
        short8 kf11 = *(const short8*)(Kh + (size_t)kr1 * HD + 32 + quad * 8);

        floatx4 s0 = {0.f, 0.f, 0.f, 0.f}, s1 = {0.f, 0.f, 0.f, 0.f};
        s0 = __builtin_amdgcn_mfma_f32_16x16x32_bf16(kf00, qf0, s0, 0, 0, 0);
        s0 = __builtin_amdgcn_mfma_f32_16x16x32_bf16(kf01, qf1, s0, 0, 0, 0);
        s1 = __builtin_amdgcn_mfma_f32_16x16x32_bf16(kf10, qf0, s1, 0, 0, 0);
        s1 = __builtin_amdgcn_mfma_f32_16x16x32_bf16(kf11, qf1, s1, 0, 0, 0);

        float sv[8];
        float mloc = -INFINITY;
#pragma unroll
        for (int r = 0; r < 4; r++) {
            const int key0 = c0 + quad * 4 + r;
            const int key1 = key0 + 16;
            sv[r]     = (key0 < NTOK) ? s0[r] * 0.125f : -1e30f;
            sv[4 + r] = (key1 < NTOK) ? s1[r] * 0.125f : -1e30f;
            mloc = fmaxf(mloc, fmaxf(sv[r], sv[4 + r]));
        }
        mloc = fmaxf(mloc, __shfl_xor(mloc, 16));
        mloc = fmaxf(mloc, __shfl_xor(mloc, 32));
        const float mnew  = fmaxf(m, mloc);
        const float alpha = __expf(m - mnew);
        float p[8], ps = 0.f;
#pragma unroll
        for (int i = 0; i < 8; i++) { p[i] = __expf(sv[i] - mnew); ps += p[i]; }
        ps += __shfl_xor(ps, 16);
        ps += __shfl_xor(ps, 32);
        l = l * alpha + ps;
        m = mnew;

#pragma unroll
        for (int r = 0; r < 4; r++) {
            Pl[qc][quad * 4 + r]      = f2bf(p[r]);
            Pl[qc][16 + quad * 4 + r] = f2bf(p[4 + r]);
        }
        if (quad == 0) alf[qc] = alpha;
        __syncthreads();

        float ar[4];
#pragma unroll
        for (int r = 0; r < 4; r++) ar[r] = alf[quad * 4 + r];
#pragma unroll
        for (int s = 0; s < 4; s++)
#pragma unroll
            for (int r = 0; r < 4; r++) o[s][r] *= ar[r];

        const short8 pf = *(const short8*)&Pl[qc][quad * 8];
#pragma unroll
        for (int s = 0; s < 4; s++) {
            const short8 vf = *(const short8*)(Vh + (size_t)(s * 16 + qc) * KPAD + c0 + quad * 8);
            o[s] = __builtin_amdgcn_mfma_f32_16x16x32_bf16(pf, vf, o[s], 0, 0, 0);
        }
        __syncthreads();
    }

    if (quad == 0) lf[qc] = l;
    __syncthreads();

#pragma unroll
    for (int r = 0; r < 4; r++) {
        const int tok = qt * 16 + quad * 4 + r;
        if (tok >= NTOK) continue;
        const float inv = 1.f / lf[quad * 4 + r];
        ushort* dst = AOb + ((size_t)(b * NTOK + tok)) * CDIM + h * HD;
#pragma unroll
        for (int s = 0; s < 4; s++) dst[s * 16 + qc] = f2bf(o[s][r] * inv);
    }
}

// ---------------------------------------------------------------------------
__global__ void cls_mean_kernel(const float* __restrict__ CLSPH,
                                float* __restrict__ clsF,
                                float* __restrict__ outCls) {
    int tid = blockIdx.x * 256 + threadIdx.x;
    if (tid >= BATCH * (NTOK - 1)) return;
    int b = tid / (NTOK - 1);
    int j = tid - b * (NTOK - 1);
    float s = 0.f;
#pragma unroll
    for (int h = 0; h < NH; h++) s += CLSPH[(size_t)(b * NH + h) * (NTOK - 1) + j];
    float v = s * (1.f / 12.f);
    clsF[tid]   = v;
    outCls[tid] = v;
}

__global__ void topk_kernel(const float* __restrict__ clsF,
                            int* __restrict__ idxI,
                            float* __restrict__ idxOut) {
    const int b = blockIdx.x;
    const int t = threadIdx.x;
    __shared__ float v[NTOK - 1];
    if (t < NTOK - 1) v[t] = clsF[b * (NTOK - 1) + t];
    __syncthreads();
    if (t < NTOK - 1) {
        float vi = v[t];
        int rank = 0;
        for (int j = 0; j < NTOK - 1; j++) {
            float vj = v[j];
            rank += (vj > vi) || (vj == vi && j < t);
        }
        if (rank < LEFT) {
            idxI[b * LEFT + rank]   = t;
            idxOut[b * LEFT + rank] = (float)t;
        }
    }
}

// index = broadcast idx over channel dim, float4-vectorized (CDIM%4==0)
__global__ void fill_index_kernel(const int* __restrict__ idxI,
                                  float* __restrict__ dst) {
    int tid = blockIdx.x * 256 + threadIdx.x;
    constexpr int C4 = CDIM / 4;
    if (tid >= BATCH * LEFT * C4) return;
    float v = (float)idxI[tid / C4];
    ((float4*)dst)[tid] = make_float4(v, v, v, v);
}

extern "C" void kernel_launch(void* const* d_in, const int* in_sizes, int n_in,
                              void* d_out, int out_size, void* d_ws, size_t ws_size,
                              hipStream_t stream) {
    const float* x      = (const float*)d_in[0];
    const float* qkv_w  = (const float*)d_in[1];  // [2304,768]
    const float* qkv_b  = (const float*)d_in[2];  // [2304]
    const float* proj_w = (const float*)d_in[3];  // [768,768]
    const float* proj_b = (const float*)d_in[4];  // [768]
    float* out = (float*)d_out;

    float*  ws    = (float*)d_ws;
    float*  clsph = ws + WS_CLSPH;
    float*  clsf  = ws + WS_CLSF;
    int*    idxi  = (int*)(ws + WS_IDXI);
    float*  q0    = ws + WS_Q0;
    ushort* xb    = (ushort*)(ws + WS_XB);
    ushort* wb    = (ushort*)(ws + WS_WB);
    ushort* pb    = (ushort*)(ws + WS_PB);
    ushort* qb    = (ushort*)(ws + WS_QB);
    ushort* kb    = (ushort*)(ws + WS_KB);
    ushort* vtb   = (ushort*)(ws + WS_VTB);
    ushort* aob   = (ushort*)(ws + WS_AOB);
    ushort* vd    = aob;   // dense-v staging aliases aob (free until attn runs)
    float*  U     = ws + WS_U;
    float*  S     = ws + WS_S;

    // 1) fp32 -> bf16 casts (+row padding to MPAD)
    {
        int n4 = MROWS * CDIM / 4, np4 = MPAD * CDIM / 4;
        cast_kernel<<<(np4 + 255) / 256, 256, 0, stream>>>(x, xb, n4, np4);
        int w4 = 3 * CDIM * CDIM / 4;
        cast_kernel<<<(w4 + 255) / 256, 256, 0, stream>>>(qkv_w, wb, w4, w4);
        int p4 = CDIM * CDIM / 4;
        cast_kernel<<<(p4 + 255) / 256, 256, 0, stream>>>(proj_w, pb, p4, p4);
    }

    // 2) Exact fp32 cls-score side path (top-k precision domain)
    q0_kernel<<<(BATCH * CDIM + 255) / 256, 256, 0, stream>>>(x, qkv_w, qkv_b, q0);
    u_kernel<<<BH, 256, 0, stream>>>(q0, qkv_w, U);
    score_kernel<<<dim3((NTOK + 3) / 4, BATCH), 256, 0, stream>>>(x, U, S);
    cls_softmax_kernel<<<BH, 64, 0, stream>>>(S, q0, qkv_b, clsph);

    // 3) QKV projection (128² MFMA, 2 blocks/CU) + q/k split, v dense
    mfma_gemm128<1, 18><<<NROWT * 18, 256, 0, stream>>>(
        xb, wb, qkv_b, nullptr, qb, kb, vd, MROWS, 3 * CDIM);

    // 3b) dense v -> transposed vtb (coalesced; zero-fills pad cols)
    v_transpose_kernel<<<BH, 256, 0, stream>>>(vd, vtb);

    // 4) MFMA flash attention -> bf16 pre-proj out (overwrites vd alias)
    attn_mfma_kernel<<<dim3(13, BH), 64, 0, stream>>>(qb, kb, vtb, aob);

    // 5) Output projection (128² MFMA) -> fp32 out
    mfma_gemm128<0, 6><<<NROWT * 6, 256, 0, stream>>>(
        aob, pb, proj_b, out + OUT_OFF_OUT, nullptr, nullptr, nullptr,
        MROWS, CDIM);

    // 6) Head-average cls attention (exact path)
    cls_mean_kernel<<<(BATCH * (NTOK - 1) + 255) / 256, 256, 0, stream>>>(
        clsph, clsf, out + OUT_OFF_CLS);

    // 7) Exact top-137 (stable descending)
    topk_kernel<<<BATCH, 256, 0, stream>>>(clsf, idxi, out + OUT_OFF_IDX);

    // 8) Broadcast indices over channels (float4)
    fill_index_kernel<<<((size_t)BATCH * LEFT * (CDIM / 4) + 255) / 256, 256, 0, stream>>>(
        idxi, out + OUT_OFF_INDEX);
}

// Round 4
// 369.864 us; speedup vs baseline: 1.0667x; 1.0452x over previous
//
#include <hip/hip_runtime.h>
#include <hip/hip_bf16.h>
#include <stdint.h>

// Problem constants
constexpr int BATCH = 64;
constexpr int NTOK  = 197;
constexpr int CDIM  = 768;
constexpr int NH    = 12;
constexpr int HD    = 64;
constexpr int MROWS = BATCH * NTOK;        // 12608
constexpr int MPAD  = 12800;               // 100 * 128 (GEMM row tiles)
constexpr int NROWT = MPAD / 128;          // 100
constexpr int LEFT  = 137;                 // int(0.7 * 196)
constexpr int KPAD  = 224;                 // keys padded (7 * 32)
constexpr int BH    = BATCH * NH;          // 768
constexpr int SPAD  = 208;                 // score row stride

// Output layout (flat float32, concatenated in return order)
constexpr size_t OUT_OFF_OUT   = 0;                                   // [64,197,768]
constexpr size_t OUT_OFF_INDEX = (size_t)BATCH * NTOK * CDIM;         // [64,137,768]
constexpr size_t OUT_OFF_IDX   = OUT_OFF_INDEX + (size_t)BATCH * LEFT * CDIM; // [64,137]
constexpr size_t OUT_OFF_CLS   = OUT_OFF_IDX + (size_t)BATCH * LEFT;  // [64,196]

// Workspace layout (float units; bf16 regions counted as elems/2)
constexpr size_t WS_CLSPH = 0;                                        // B*H*196
constexpr size_t WS_CLSF  = WS_CLSPH + (size_t)BH * (NTOK - 1);
constexpr size_t WS_IDXI  = WS_CLSF  + (size_t)BATCH * (NTOK - 1);
constexpr size_t WS_Q0    = WS_IDXI  + (size_t)BATCH * LEFT;          // [64,768]
constexpr size_t WS_XB    = WS_Q0  + (size_t)BATCH * CDIM;            // [MPAD,768] bf16
constexpr size_t WS_WB    = WS_XB  + (size_t)MPAD * CDIM / 2;         // [2304,768] bf16
constexpr size_t WS_PB    = WS_WB  + (size_t)3 * CDIM * CDIM / 2;     // [768,768] bf16
constexpr size_t WS_QB    = WS_PB  + (size_t)CDIM * CDIM / 2;         // [BH,197,64] bf16
constexpr size_t WS_KB    = WS_QB  + (size_t)BH * NTOK * HD / 2;      // [BH,197,64] bf16
constexpr size_t WS_VTB   = WS_KB  + (size_t)BH * NTOK * HD / 2;      // [BH,64,224] bf16
constexpr size_t WS_AOB   = WS_VTB + (size_t)BH * HD * KPAD / 2;      // [MPAD,768] bf16
constexpr size_t WS_U     = WS_AOB + (size_t)MPAD * CDIM / 2;         // [BH,768] fp32
constexpr size_t WS_S     = WS_U   + (size_t)BH * CDIM;               // [BH,208] fp32

typedef __attribute__((ext_vector_type(8))) short short8;
typedef __attribute__((ext_vector_type(4))) float floatx4;

__device__ __forceinline__ ushort f2bf(float x) {
    __hip_bfloat16 h = __float2bfloat16(x);
    return *(ushort*)&h;
}

// async global->LDS, 16B per lane; LDS dest must be wave-uniform base + lane*16
__device__ __forceinline__ void load_lds16(const ushort* g, ushort* l) {
    __builtin_amdgcn_global_load_lds(
        (const __attribute__((address_space(1))) uint32_t*)(uintptr_t)g,
        (__attribute__((address_space(3))) uint32_t*)(uint32_t)(uintptr_t)l,
        16, 0, 0);
}

// ---------------------------------------------------------------------------
// Fused fp32 -> bf16 cast of x (padded to MPAD rows), qkv_w, proj_w.
// One dispatch instead of three.
// ---------------------------------------------------------------------------
constexpr int X_N4  = MROWS * CDIM / 4;         // valid x float4s
constexpr int X_NP4 = MPAD * CDIM / 4;          // padded x float4s
constexpr int W_N4  = 3 * CDIM * CDIM / 4;
constexpr int P_N4  = CDIM * CDIM / 4;
constexpr int CAST_TOTAL = X_NP4 + W_N4 + P_N4; // 3,047,424 (multiple of 256)

__global__ __launch_bounds__(256) void cast_all_kernel(const float* __restrict__ x,
                                                       const float* __restrict__ qkv_w,
                                                       const float* __restrict__ proj_w,
                                                       ushort* __restrict__ xb,
                                                       ushort* __restrict__ wb,
                                                       ushort* __restrict__ pb) {
    int i = blockIdx.x * 256 + threadIdx.x;
    const float* src;
    ushort* dst;
    int j, valid;
    if (i < X_NP4) {
        src = x; dst = xb; j = i; valid = (j < X_N4);
    } else if (i < X_NP4 + W_N4) {
        src = qkv_w; dst = wb; j = i - X_NP4; valid = 1;
    } else if (i < CAST_TOTAL) {
        src = proj_w; dst = pb; j = i - X_NP4 - W_N4; valid = 1;
    } else {
        return;
    }
    ushort4 h4 = make_ushort4(0, 0, 0, 0);
    if (valid) {
        float4 a = ((const float4*)src)[j];
        h4 = make_ushort4(f2bf(a.x), f2bf(a.y), f2bf(a.z), f2bf(a.w));
    }
    ((ushort4*)dst)[j] = h4;
}

// ---------------------------------------------------------------------------
// Exact fp32 q row-0 projection: q0[b, c] = x[b,0,:] . qkv_w[c,:] + qkv_b[c]
// ---------------------------------------------------------------------------
__global__ __launch_bounds__(256) void q0_kernel(const float* __restrict__ x,
                                                 const float* __restrict__ qkv_w,
                                                 const float* __restrict__ qkv_b,
                                                 float* __restrict__ q0) {
    int tid = blockIdx.x * 256 + threadIdx.x;
    if (tid >= BATCH * CDIM) return;
    int b = tid / CDIM, c = tid - b * CDIM;
    const float* xr = x + (size_t)b * NTOK * CDIM;
    const float* wr = qkv_w + (size_t)c * CDIM;
    float s = 0.f;
    for (int k = 0; k < CDIM; k += 4) {
        float4 xv = *(const float4*)(xr + k);
        float4 wv = *(const float4*)(wr + k);
        s += xv.x * wv.x + xv.y * wv.y + xv.z * wv.z + xv.w * wv.w;
    }
    q0[tid] = s + qkv_b[c];
}

// ---------------------------------------------------------------------------
// u[bh, c] = sum_d q0[b, h*64+d] * Wk[h*64+d, c]   (Wk = qkv_w rows 768..1535)
// ---------------------------------------------------------------------------
__global__ __launch_bounds__(256) void u_kernel(const float* __restrict__ q0,
                                                const float* __restrict__ qkv_w,
                                                float* __restrict__ U) {
    const int bh = blockIdx.x;
    const int b  = bh / NH;
    const int h  = bh - b * NH;
    const int t  = threadIdx.x;

    __shared__ float q0s[HD];
    if (t < HD) q0s[t] = q0[(size_t)b * CDIM + h * HD + t];
    __syncthreads();

    const float* wk = qkv_w + (size_t)(CDIM + h * HD) * CDIM;
    float a0 = 0.f, a1 = 0.f, a2 = 0.f;
    for (int d = 0; d < HD; d++) {
        const float qd = q0s[d];
        const float* row = wk + (size_t)d * CDIM;
        a0 = fmaf(qd, row[t],       a0);
        a1 = fmaf(qd, row[t + 256], a1);
        a2 = fmaf(qd, row[t + 512], a2);
    }
    float* ub = U + (size_t)bh * CDIM;
    ub[t] = a0; ub[t + 256] = a1; ub[t + 512] = a2;
}

// ---------------------------------------------------------------------------
// S[bh, j] = u[bh,:] . x[b,j,:]   — 4 waves per block, one (j,b) per wave.
// ---------------------------------------------------------------------------
__global__ __launch_bounds__(256) void score_kernel(const float* __restrict__ x,
                                                    const float* __restrict__ U,
                                                    float* __restrict__ S) {
    const int wv   = threadIdx.x >> 6;
    const int lane = threadIdx.x & 63;
    const int j    = blockIdx.x * 4 + wv;
    const int b    = blockIdx.y;
    if (j >= NTOK) return;

    const float* xr = x + ((size_t)b * NTOK + j) * CDIM;
    float4 xv[3];
#pragma unroll
    for (int i = 0; i < 3; i++) xv[i] = *(const float4*)(xr + lane * 4 + i * 256);

    for (int h = 0; h < NH; h++) {
        const float* ur = U + (size_t)(b * NH + h) * CDIM;
        float s = 0.f;
#pragma unroll
        for (int i = 0; i < 3; i++) {
            float4 uv = *(const float4*)(ur + lane * 4 + i * 256);
            s += xv[i].x * uv.x + xv[i].y * uv.y + xv[i].z * uv.z + xv[i].w * uv.w;
        }
#pragma unroll
        for (int off = 32; off >= 1; off >>= 1) s += __shfl_xor(s, off);
        if (lane == 0) S[(size_t)(b * NH + h) * SPAD + j] = s;
    }
}

// ---------------------------------------------------------------------------
// Softmax of cls row per bh: s_j = (S[j] + q0_h.bk_h) * scale; probs for j>=1.
// ---------------------------------------------------------------------------
__global__ __launch_bounds__(64) void cls_softmax_kernel(const float* __restrict__ S,
                                                         const float* __restrict__ q0,
                                                         const float* __restrict__ qkv_b,
                                                         float* __restrict__ CLSPH) {
    const int bh   = blockIdx.x;
    const int b    = bh / NH;
    const int h    = bh - b * NH;
    const int lane = threadIdx.x;

    float qb = q0[(size_t)b * CDIM + h * HD + lane] * qkv_b[CDIM + h * HD + lane];
#pragma unroll
    for (int off = 32; off >= 1; off >>= 1) qb += __shfl_xor(qb, off);

    const float* Sr = S + (size_t)bh * SPAD;
    float sv[4];
    float mloc = -INFINITY;
#pragma unroll
    for (int i = 0; i < 4; i++) {
        const int j = lane + i * 64;
        sv[i] = (j < NTOK) ? (Sr[j] + qb) * 0.125f : -INFINITY;
        mloc = fmaxf(mloc, sv[i]);
    }
#pragma unroll
    for (int off = 32; off >= 1; off >>= 1) mloc = fmaxf(mloc, __shfl_xor(mloc, off));

    float pv[4], ls = 0.f;
#pragma unroll
    for (int i = 0; i < 4; i++) { pv[i] = expf(sv[i] - mloc); ls += pv[i]; }  // exp(-inf)=0
#pragma unroll
    for (int off = 32; off >= 1; off >>= 1) ls += __shfl_xor(ls, off);

    const float inv = 1.f / ls;
#pragma unroll
    for (int i = 0; i < 4; i++) {
        const int j = lane + i * 64;
        if (j >= 1 && j < NTOK)
            CLSPH[(size_t)bh * (NTOK - 1) + (j - 1)] = pv[i] * inv;
    }
}

// ---------------------------------------------------------------------------
// 128x128 / BK=32 / 4-wave bf16 MFMA GEMM — the verified m97 geometry:
// 32 KiB LDS double-buffer + __launch_bounds__(256,4) -> 4 blocks/CU resident
// so cross-block wave overlap (m114) hides the per-K-step barrier drain
// (round-3's BK=64/64KiB was the m132 2-blocks/CU regression regime).
// - T2 XOR swizzle (4 slots/row): phys 16B slot = logical ^ (row&3);
//   gload_lds writes linearly so the *global source* is inverse-swizzled
//   and the ds_read applies the same XOR (rule #21).
// - bijective XCD-aware block swizzle for A-panel L2 locality.
// MODE 0: fp32 row-major O0f[Mvalid, N].
// MODE 1: qkv split (bf16): q -> O0q[bh][tok][64], k -> O1k[bh][tok][64],
//         v -> DENSE O2vd[m][768] (32B-segment stores; transposed later).
// ---------------------------------------------------------------------------
template <int MODE, int NCOLT>
__global__ __launch_bounds__(256, 4) void mfma_gemm128(
    const ushort* __restrict__ A, const ushort* __restrict__ W,
    const float* __restrict__ bias,
    float* __restrict__ O0f, ushort* __restrict__ O0q,
    ushort* __restrict__ O1k, ushort* __restrict__ O2vd,
    int Mvalid, int N) {
    constexpr int K   = CDIM;               // 768
    constexpr int BK  = 32;
    constexpr int NTK = K / BK;             // 24
    __shared__ ushort sA[2 * 128 * BK];     // 16 KiB
    __shared__ ushort sB[2 * 128 * BK];     // 16 KiB

    const int t    = threadIdx.x;
    const int lane = t & 63;
    const int w    = t >> 6;
    const int wm   = (w >> 1) * 64;         // M-half of tile
    const int wn   = (w & 1) * 64;          // N-half of tile
    const int fr   = lane & 15;
    const int fq   = lane >> 4;             // 0..3
    const int f3   = lane & 3;              // == fr & 3

    // bijective XCD-aware swizzle (m204): contiguous wgid chunk per XCD
    int row, col;
    {
        constexpr int nwg = NROWT * NCOLT;
        constexpr int q = nwg >> 3, r = nwg & 7;
        const int xcd = blockIdx.x & 7, lin = blockIdx.x >> 3;
        const int wg = (xcd < r ? xcd * (q + 1) : r * (q + 1) + (xcd - r) * q) + lin;
        row = wg / NCOLT; col = wg - row * NCOLT;
    }
    const int rowBase = row * 128;
    const int colBase = col * 128;

    // stage one 128x32 tile (8 KB): linear LDS dest, inverse-swizzled source
    auto stage = [&](const ushort* __restrict__ G, ushort* dst, int grow0, int kt) {
#pragma unroll
        for (int i = 0; i < 2; ++i) {
            const int l  = i * 256 + t;
            const int rl = l >> 2;                       // row (4 thr/row)
            const int sl = (l & 3) ^ (rl & 3);           // swizzled 16B slot
            load_lds16(G + (size_t)(grow0 + rl) * K + kt * BK + sl * 8,
                       dst + l * 8);
        }
    };

    floatx4 acc[4][4];
#pragma unroll
    for (int i = 0; i < 4; ++i)
#pragma unroll
        for (int j = 0; j < 4; ++j)
#pragma unroll
            for (int r2 = 0; r2 < 4; ++r2) acc[i][j][r2] = 0.f;

    // read-side swizzled slot offset (ushort units): logical slot fq
    const int s0 = (fq ^ f3) * 8;

    // prologue: tile 0 -> buffer 0
    stage(A, sA, rowBase, 0);
    stage(W, sB, colBase, 0);

    for (int kt = 0; kt < NTK; ++kt) {
        __syncthreads();                     // drains vm+lgkm: buf[cur] ready,
                                             // buf[cur^1] reads complete
        const int cb = (kt & 1) << 12;       // current buffer (ushort offset)
        if (kt + 1 < NTK) {                  // prefetch next tile
            stage(A, sA + (cb ^ 4096), rowBase, kt + 1);
            stage(W, sB + (cb ^ 4096), colBase, kt + 1);
        }

        const ushort* pa = sA + cb + (wm + fr) * BK;
        const ushort* pb = sB + cb + (wn + fr) * BK;
        short8 af[4], bf[4];
#pragma unroll
        for (int i = 0; i < 4; ++i) {
            af[i] = *(const short8*)(pa + i * 512 + s0);
            bf[i] = *(const short8*)(pb + i * 512 + s0);
        }
#pragma unroll
        for (int i = 0; i < 4; ++i)
#pragma unroll
            for (int j = 0; j < 4; ++j)
                acc[i][j] = __builtin_amdgcn_mfma_f32_16x16x32_bf16(
                    af[i], bf[j], acc[i][j], 0, 0, 0);
    }

    // epilogue: C/D layout col(n)=lane&15, row(m)=(lane>>4)*4+reg
#pragma unroll
    for (int j = 0; j < 4; ++j) {
        const int nn = colBase + wn + j * 16 + fr;
        const float bq = bias[nn];
        if (MODE == 0) {
#pragma unroll
            for (int i = 0; i < 4; ++i) {
                const int mb = rowBase + wm + i * 16 + fq * 4;
#pragma unroll
                for (int r2 = 0; r2 < 4; ++r2) {
                    const int mm = mb + r2;
                    if (mm < Mvalid) O0f[(size_t)mm * N + nn] = acc[i][j][r2] + bq;
                }
            }
        } else {
            const int which = nn / CDIM;     // wave-uniform per col-tile
            const int nc    = nn - which * CDIM;
            const int h     = nc >> 6;
            const int d     = nc & 63;
#pragma unroll
            for (int i = 0; i < 4; ++i) {
                const int mb = rowBase + wm + i * 16 + fq * 4;
#pragma unroll
                for (int r2 = 0; r2 < 4; ++r2) {
                    const int mm = mb + r2;
                    if (mm < Mvalid) {
                        const int b   = mm / NTOK;
                        const int tok = mm - b * NTOK;
                        const int bh  = b * NH + h;
                        const ushort val = f2bf(acc[i][j][r2] + bq);
                        if (which == 0)      O0q[((size_t)bh * NTOK + tok) * HD + d] = val;
                        else if (which == 1) O1k[((size_t)bh * NTOK + tok) * HD + d] = val;
                        else                 O2vd[(size_t)mm * CDIM + nc] = val;  // dense
                    }
                }
            }
        }
    }
}

// ---------------------------------------------------------------------------
// Vd[b*197+tok][768] (dense v, bf16) -> Vtb[bh][d][KPAD] via LDS transpose.
// Coalesced 128B row reads, 448B row writes; zero-fills pad cols 197..223.
// ---------------------------------------------------------------------------
__global__ __launch_bounds__(256) void v_transpose_kernel(const ushort* __restrict__ Vd,
                                                          ushort* __restrict__ Vtb) {
    const int bh = blockIdx.x;             // 0..767
    const int b  = bh / NH;
    const int h  = bh - b * NH;
    const int t  = threadIdx.x;

    __shared__ ushort tile[HD][KPAD + 9];  // odd pad stride vs bank conflicts

    const int d  = t & 63;
    const int tt = t >> 6;                 // 0..3
    const ushort* src = Vd + (size_t)b * NTOK * CDIM + h * HD + d;
    for (int tok0 = 0; tok0 < KPAD; tok0 += 4) {
        const int tok = tok0 + tt;
        ushort v = 0;
        if (tok < NTOK) v = src[(size_t)tok * CDIM];
        tile[d][tok] = v;
    }
    __syncthreads();

    uint* dst = (uint*)(Vtb + (size_t)bh * HD * KPAD);
    constexpr int C2 = KPAD / 2;           // 112 u32 per d-row
    for (int idx = t; idx < HD * C2; idx += 256) {
        const int dd = idx / C2;
        const int c  = idx - dd * C2;
        const uint lo = tile[dd][2 * c];
        const uint hi = tile[dd][2 * c + 1];
        dst[dd * C2 + c] = lo | (hi << 16);
    }
}

// ---------------------------------------------------------------------------
// MFMA flash attention: one wave (64 threads) per (q-tile, b*h).
// S^T = K.Q^T so queries sit in C-columns; online softmax per-lane + two
// shfl_xor quad-reduces. P via 1KB LDS roundtrip; PV uses transposed-V frags.
// ---------------------------------------------------------------------------
__global__ __launch_bounds__(64) void attn_mfma_kernel(const ushort* __restrict__ Qb,
                                                       const ushort* __restrict__ Kb,
                                                       const ushort* __restrict__ Vtb,
                                                       ushort* __restrict__ AOb) {
    const int qt = blockIdx.x;          // 0..12
    const int bh = blockIdx.y;          // 0..767
    const int b  = bh / NH;
    const int h  = bh - b * NH;
    const int lane = threadIdx.x;
    const int qc   = lane & 15;
    const int quad = lane >> 4;

    __shared__ ushort Pl[16][32];
    __shared__ float  alf[16], lf[16];

    const ushort* Qh = Qb  + (size_t)bh * NTOK * HD;
    const ushort* Kh = Kb  + (size_t)bh * NTOK * HD;
    const ushort* Vh = Vtb + (size_t)bh * HD * KPAD;

    const int qrow = min(qt * 16 + qc, NTOK - 1);
    const short8 qf0 = *(const short8*)(Qh + (size_t)qrow * HD + quad * 8);
    const short8 qf1 = *(const short8*)(Qh + (size_t)qrow * HD + 32 + quad * 8);

    floatx4 o[4];
#pragma unroll
    for (int s = 0; s < 4; s++)
#pragma unroll
        for (int r = 0; r < 4; r++) o[s][r] = 0.f;
    float m = -INFINITY, l = 0.f;

    for (int c0 = 0; c0 < NTOK; c0 += 32) {
        const int kr0 = min(c0 + qc, NTOK - 1);
        const int kr1 = min(c0 + 16 + qc, NTOK - 1);
        short8 kf00 = *(const short8*)(Kh + (size_t)kr0 * HD + quad * 8);
        short8 kf01 = *(const short8*)(Kh + (size_t)kr0 * HD + 32 + quad * 8);
        short8 kf10 = *(const short8*)(Kh + (size_t)kr1 * HD + quad * 8);
        short8 kf11 = *(const short8*)(Kh + (size_t)kr1 * HD + 32 + quad * 8);

        floatx4 s0 = {0.f, 0.f, 0.f, 0.f}, s1 = {0.f, 0.f, 0.f, 0.f};
        s0 = __builtin_amdgcn_mfma_f32_16x16x32_bf16(kf00, qf0, s0, 0, 0, 0);
        s0 = __builtin_amdgcn_mfma_f32_16x16x32_bf16(kf01, qf1, s0, 0, 0, 0);
        s1 = __builtin_amdgcn_mfma_f32_16x16x32_bf16(kf10, qf0, s1, 0, 0, 0);
        s1 = __builtin_amdgcn_mfma_f32_16x16x32_bf16(kf11, qf1, s1, 0, 0, 0);

        float sv[8];
        float mloc = -INFINITY;
#pragma unroll
        for (int r = 0; r < 4; r++) {
            const int key0 = c0 + quad * 4 + r;
            const int key1 = key0 + 16;
            sv[r]     = (key0 < NTOK) ? s0[r] * 0.125f : -1e30f;
            sv[4 + r] = (key1 < NTOK) ? s1[r] * 0.125f : -1e30f;
            mloc = fmaxf(mloc, fmaxf(sv[r], sv[4 + r]));
        }
        mloc = fmaxf(mloc, __shfl_xor(mloc, 16));
        mloc = fmaxf(mloc, __shfl_xor(mloc, 32));
        const float mnew  = fmaxf(m, mloc);
        const float alpha = __expf(m - mnew);
        float p[8], ps = 0.f;
#pragma unroll
        for (int i = 0; i < 8; i++) { p[i] = __expf(sv[i] - mnew); ps += p[i]; }
        ps += __shfl_xor(ps, 16);
        ps += __shfl_xor(ps, 32);
        l = l * alpha + ps;
        m = mnew;

#pragma unroll
        for (int r = 0; r < 4; r++) {
            Pl[qc][quad * 4 + r]      = f2bf(p[r]);
            Pl[qc][16 + quad * 4 + r] = f2bf(p[4 + r]);
        }
        if (quad == 0) alf[qc] = alpha;
        __syncthreads();

        float ar[4];
#pragma unroll
        for (int r = 0; r < 4; r++) ar[r] = alf[quad * 4 + r];
#pragma unroll
        for (int s = 0; s < 4; s++)
#pragma unroll
            for (int r = 0; r < 4; r++) o[s][r] *= ar[r];

        const short8 pf = *(const short8*)&Pl[qc][quad * 8];
#pragma unroll
        for (int s = 0; s < 4; s++) {
            const short8 vf = *(const short8*)(Vh + (size_t)(s * 16 + qc) * KPAD + c0 + quad * 8);
            o[s] = __builtin_amdgcn_mfma_f32_16x16x32_bf16(pf, vf, o[s], 0, 0, 0);
        }
        __syncthreads();
    }

    if (quad == 0) lf[qc] = l;
    __syncthreads();

#pragma unroll
    for (int r = 0; r < 4; r++) {
        const int tok = qt * 16 + quad * 4 + r;
        if (tok >= NTOK) continue;
        const float inv = 1.f / lf[quad * 4 + r];
        ushort* dst = AOb + ((size_t)(b * NTOK + tok)) * CDIM + h * HD;
#pragma unroll
        for (int s = 0; s < 4; s++) dst[s * 16 + qc] = f2bf(o[s][r] * inv);
    }
}

// ---------------------------------------------------------------------------
// Fused head-average + exact top-137 (stable descending) + cls output.
// One block per batch; replaces cls_mean_kernel + topk_kernel.
// ---------------------------------------------------------------------------
__global__ __launch_bounds__(256) void topk_kernel(const float* __restrict__ CLSPH,
                                                   int* __restrict__ idxI,
                                                   float* __restrict__ idxOut,
                                                   float* __restrict__ outCls) {
    const int b = blockIdx.x;
    const int t = threadIdx.x;
    __shared__ float v[NTOK - 1];
    if (t < NTOK - 1) {
        float s = 0.f;
#pragma unroll
        for (int h = 0; h < NH; h++)
            s += CLSPH[(size_t)(b * NH + h) * (NTOK - 1) + t];
        const float val = s * (1.f / 12.f);
        v[t] = val;
        outCls[b * (NTOK - 1) + t] = val;
    }
    __syncthreads();
    if (t < NTOK - 1) {
        float vi = v[t];
        int rank = 0;
        for (int j = 0; j < NTOK - 1; j++) {
            float vj = v[j];
            rank += (vj > vi) || (vj == vi && j < t);
        }
        if (rank < LEFT) {
            idxI[b * LEFT + rank]   = t;
            idxOut[b * LEFT + rank] = (float)t;
        }
    }
}

// index = broadcast idx over channel dim, float4-vectorized (CDIM%4==0)
__global__ void fill_index_kernel(const int* __restrict__ idxI,
                                  float* __restrict__ dst) {
    int tid = blockIdx.x * 256 + threadIdx.x;
    constexpr int C4 = CDIM / 4;
    if (tid >= BATCH * LEFT * C4) return;
    float v = (float)idxI[tid / C4];
    ((float4*)dst)[tid] = make_float4(v, v, v, v);
}

extern "C" void kernel_launch(void* const* d_in, const int* in_sizes, int n_in,
                              void* d_out, int out_size, void* d_ws, size_t ws_size,
                              hipStream_t stream) {
    const float* x      = (const float*)d_in[0];
    const float* qkv_w  = (const float*)d_in[1];  // [2304,768]
    const float* qkv_b  = (const float*)d_in[2];  // [2304]
    const float* proj_w = (const float*)d_in[3];  // [768,768]
    const float* proj_b = (const float*)d_in[4];  // [768]
    float* out = (float*)d_out;

    float*  ws    = (float*)d_ws;
    float*  clsph = ws + WS_CLSPH;
    int*    idxi  = (int*)(ws + WS_IDXI);
    float*  q0    = ws + WS_Q0;
    ushort* xb    = (ushort*)(ws + WS_XB);
    ushort* wb    = (ushort*)(ws + WS_WB);
    ushort* pb    = (ushort*)(ws + WS_PB);
    ushort* qb    = (ushort*)(ws + WS_QB);
    ushort* kb    = (ushort*)(ws + WS_KB);
    ushort* vtb   = (ushort*)(ws + WS_VTB);
    ushort* aob   = (ushort*)(ws + WS_AOB);
    ushort* vd    = aob;   // dense-v staging aliases aob (free until attn runs)
    float*  U     = ws + WS_U;
    float*  S     = ws + WS_S;

    // 1) fused fp32 -> bf16 casts (x padded to MPAD, qkv_w, proj_w)
    cast_all_kernel<<<CAST_TOTAL / 256, 256, 0, stream>>>(x, qkv_w, proj_w, xb, wb, pb);

    // 2) Exact fp32 cls-score side path (top-k precision domain)
    q0_kernel<<<(BATCH * CDIM + 255) / 256, 256, 0, stream>>>(x, qkv_w, qkv_b, q0);
    u_kernel<<<BH, 256, 0, stream>>>(q0, qkv_w, U);
    score_kernel<<<dim3((NTOK + 3) / 4, BATCH), 256, 0, stream>>>(x, U, S);
    cls_softmax_kernel<<<BH, 64, 0, stream>>>(S, q0, qkv_b, clsph);

    // 3) QKV projection (128²/BK32 MFMA, 4 blocks/CU) + q/k split, v dense
    mfma_gemm128<1, 18><<<NROWT * 18, 256, 0, stream>>>(
        xb, wb, qkv_b, nullptr, qb, kb, vd, MROWS, 3 * CDIM);

    // 3b) dense v -> transposed vtb (coalesced; zero-fills pad cols)
    v_transpose_kernel<<<BH, 256, 0, stream>>>(vd, vtb);

    // 4) MFMA flash attention -> bf16 pre-proj out (overwrites vd alias)
    attn_mfma_kernel<<<dim3(13, BH), 64, 0, stream>>>(qb, kb, vtb, aob);

    // 5) Output projection (128²/BK32 MFMA) -> fp32 out
    mfma_gemm128<0, 6><<<NROWT * 6, 256, 0, stream>>>(
        aob, pb, proj_b, out + OUT_OFF_OUT, nullptr, nullptr, nullptr,
        MROWS, CDIM);

    // 6) Fused head-average + exact top-137 + cls output
    topk_kernel<<<BATCH, 256, 0, stream>>>(clsph, idxi, out + OUT_OFF_IDX,
                                           out + OUT_OFF_CLS);

    // 7) Broadcast indices over channels (float4)
    fill_index_kernel<<<((size_t)BATCH * LEFT * (CDIM / 4) + 255) / 256, 256, 0, stream>>>(
        idxi, out + OUT_OFF_INDEX);
}